// Round 2
// baseline (239.766 us; speedup 1.0000x reference)
//
#include <hip/hip_runtime.h>
#include <hip/hip_bf16.h>

// Problem constants
#define B_ROWS 4096
#define N_ROWS 8192
#define D_DIM 256
#define PHI 0.95f
// exp(sim-2) = exp2((2*raw-2)*log2e) = exp2(raw*C1 - C1)
#define C1 2.8853900817779268f

// Symmetric tiling: upper-triangle blocks of 128x128 rows x cols.
#define TILE 128
#define T_TILES (N_ROWS / TILE)                 // 64
#define NBLK (T_TILES * (T_TILES + 1) / 2)      // 2080

typedef __attribute__((ext_vector_type(8))) short short8;    // 8 x bf16
typedef __attribute__((ext_vector_type(4))) float floatx4;   // MFMA C/D

static __device__ __forceinline__ unsigned short f2bf(float f) {
    unsigned u = __builtin_bit_cast(unsigned, f);
    unsigned r = (u + 0x7fffu + ((u >> 16) & 1u)) >> 16;   // RNE
    return (unsigned short)r;
}
static __device__ __forceinline__ float bf2f(unsigned short s) {
    unsigned u = ((unsigned)s) << 16;
    return __builtin_bit_cast(float, u);
}
static __device__ __forceinline__ float fast_exp2(float x) {
#if __has_builtin(__builtin_amdgcn_exp2f)
    return __builtin_amdgcn_exp2f(x);
#else
    return __expf(x * 0.6931471805599453f);
#endif
}

// Kernel 1: fused normalize + positive-pair dot.
// Positive partner of row i (view 0) is row i+B (view 1) == the SAME feature
// row's other view, adjacent 256 floats in memory. One wave handles one pair:
// normalizes both views (bitwise-identical math to the baseline
// normalize_kernel), writes X[i], X[i+B], and the pos-dot computed from the
// bf16 values with the exact op order of the baseline pos_kernel. Also zeroes
// S, out, and (if present) the ticket counter.
__global__ __launch_bounds__(256) void norm_pos_kernel(
        const float* __restrict__ feat, unsigned short* __restrict__ X,
        float* __restrict__ S, float* __restrict__ rawp,
        float* __restrict__ out, unsigned int* __restrict__ done) {
    int pair = blockIdx.x * 4 + (threadIdx.x >> 6);   // 0..4095
    int lane = threadIdx.x & 63;
    const float* src = feat + (size_t)pair * (2 * D_DIM);
    float4 v0 = ((const float4*)src)[lane];           // view 0
    float4 v1 = ((const float4*)(src + D_DIM))[lane]; // view 1
    float ss0 = v0.x * v0.x + v0.y * v0.y + v0.z * v0.z + v0.w * v0.w;
    float ss1 = v1.x * v1.x + v1.y * v1.y + v1.z * v1.z + v1.w * v1.w;
    #pragma unroll
    for (int off = 32; off; off >>= 1) {
        ss0 += __shfl_xor(ss0, off);
        ss1 += __shfl_xor(ss1, off);
    }
    float inv0 = 1.0f / fmaxf(sqrtf(ss0), 1e-12f);
    float inv1 = 1.0f / fmaxf(sqrtf(ss1), 1e-12f);
    ushort4 o0, o1;
    o0.x = f2bf(v0.x * inv0); o0.y = f2bf(v0.y * inv0);
    o0.z = f2bf(v0.z * inv0); o0.w = f2bf(v0.w * inv0);
    o1.x = f2bf(v1.x * inv1); o1.y = f2bf(v1.y * inv1);
    o1.z = f2bf(v1.z * inv1); o1.w = f2bf(v1.w * inv1);
    ((ushort4*)(X + (size_t)pair * D_DIM))[lane] = o0;
    ((ushort4*)(X + (size_t)(pair + B_ROWS) * D_DIM))[lane] = o1;
    // pos dot, same numerics as baseline pos_kernel (bf16 values, fp32 accum)
    float d = bf2f(o0.x) * bf2f(o1.x) + bf2f(o0.y) * bf2f(o1.y)
            + bf2f(o0.z) * bf2f(o1.z) + bf2f(o0.w) * bf2f(o1.w);
    #pragma unroll
    for (int off = 32; off; off >>= 1) d += __shfl_xor(d, off);
    if (lane == 0) {
        rawp[pair] = d; rawp[pair + B_ROWS] = d;   // symmetric
        S[pair] = 0.0f; S[pair + B_ROWS] = 0.0f;
    }
    if (blockIdx.x == 0 && threadIdx.x == 0) {
        out[0] = 0.0f;
        if (done) *done = 0u;
    }
}

// Kernel 2: symmetric Gram + masked exp-sum (+ last-block finalize if a
// ticket counter is available). One block per upper-triangle tile pair
// (I,J), J>=I, 128x128 tile. 4 waves in a 2x2 quadrant layout; each wave:
// 64 rows (A in regs) x 64 cols (B from a single 64KB swizzled LDS stage).
// Each element's masked exp feeds S[row] (row-sum) and, for off-diagonal
// tiles, S[col] (transpose-sum).
__global__ __launch_bounds__(256, 2) void sym_sim_kernel(
        const unsigned short* __restrict__ X, float* __restrict__ S,
        const float* __restrict__ rawp, float* __restrict__ out,
        unsigned int* __restrict__ done) {
    // 64 KiB: B-panel rows J*128..+128, 256 bf16 each, chunk-XOR swizzled
    // (16B chunk ch of row r stored at ch ^ (r&7)) -> quarter-wave reads are
    // 2-way bank aliased (free) for both ds_write_b128 and ds_read_b128.
    __shared__ unsigned short tile[TILE * D_DIM];

    const int tid  = threadIdx.x;
    const int wave = tid >> 6;
    const int lane = tid & 63;
    const int quad = lane >> 4;
    const int l16  = lane & 15;

    // upper-triangle decode: off(I) = I*(2T-I+1)/2, J = I + (bid - off(I))
    const int bid = (int)blockIdx.x;
    int I = (int)((2.0f * T_TILES + 1.0f
             - sqrtf((float)((2 * T_TILES + 1) * (2 * T_TILES + 1) - 8 * bid))) * 0.5f);
    while (((I + 1) * (2 * T_TILES - I)) / 2 <= bid) I++;
    while ((I * (2 * T_TILES - I + 1)) / 2 > bid) I--;
    const int J = I + bid - (I * (2 * T_TILES - I + 1)) / 2;

    const int wr = wave >> 1;   // row half 0..1
    const int wc = wave & 1;    // col half 0..1
    const int rowbase = I * TILE + wr * 64;
    const int colbase = J * TILE + wc * 64;

    // A fragments: 4 row-sets x 8 K-steps; lane holds A[m=l16][k=quad*8+j]
    short8 af[4][8];
    #pragma unroll
    for (int s = 0; s < 4; s++) {
        const unsigned short* ap = X + (size_t)(rowbase + s * 16 + l16) * D_DIM + quad * 8;
        #pragma unroll
        for (int ks = 0; ks < 8; ks++)
            af[s][ks] = *(const short8*)(ap + ks * 32);
    }

    // Stage B panel (single stage, single barrier for the whole block)
    #pragma unroll
    for (int p = 0; p < 16; p++) {
        int idx = p * 256 + tid;
        int r   = idx >> 5;        // 0..127
        int ch  = idx & 31;        // 16B chunk
        short8 d = *(const short8*)(X + (size_t)(J * TILE + r) * D_DIM + ch * 8);
        *(short8*)(tile + r * D_DIM + ((ch ^ (r & 7)) * 8)) = d;
    }
    __syncthreads();

    float sacc[4][4];
    #pragma unroll
    for (int s = 0; s < 4; s++)
        #pragma unroll
        for (int r = 0; r < 4; r++) sacc[s][r] = 0.0f;
    float cacc[4];

    #pragma unroll
    for (int st = 0; st < 4; st++) {            // 4 col-subtiles of 16
        const int brow = wc * 64 + st * 16 + l16;
        const unsigned short* bp = tile + brow * D_DIM;
        const int bsw = brow & 7;
        floatx4 acc[4];
        #pragma unroll
        for (int s = 0; s < 4; s++) acc[s] = (floatx4){0.f, 0.f, 0.f, 0.f};
        #pragma unroll
        for (int ks = 0; ks < 8; ks++) {        // K = 256
            short8 bfrag = *(const short8*)(bp + (((ks * 4 + quad) ^ bsw) * 8));
            #pragma unroll
            for (int s = 0; s < 4; s++)
                acc[s] = __builtin_amdgcn_mfma_f32_16x16x32_bf16(af[s][ks], bfrag, acc[s], 0, 0, 0);
        }
        // Epilogue: masked exp feeds row-acc AND col-acc (6 VALU/elem).
        float cs = 0.0f;
        #pragma unroll
        for (int s = 0; s < 4; s++)
            #pragma unroll
            for (int r = 0; r < 4; r++) {
                float raw = acc[s][r];
                float e = fast_exp2(fmaf(raw, C1, -C1));
                e = (raw < PHI) ? e : 0.0f;
                sacc[s][r] += e;
                cs += e;
            }
        cacc[st] = cs;
    }

    // Row sums: reduce over the 16 cols (l16) of each quad-group.
    #pragma unroll
    for (int s = 0; s < 4; s++)
        #pragma unroll
        for (int r = 0; r < 4; r++) {
            float v = sacc[s][r];
            v += __shfl_xor(v, 1);
            v += __shfl_xor(v, 2);
            v += __shfl_xor(v, 4);
            v += __shfl_xor(v, 8);
            if (l16 == r) atomicAdd(&S[rowbase + s * 16 + quad * 4 + r], v);
        }
    // Transpose (col) sums: reduce over quads; skip on diagonal tiles
    // (a diagonal tile already counts every (i,j) of its square once).
    if (I != J) {
        #pragma unroll
        for (int st = 0; st < 4; st++) {
            float v = cacc[st];
            v += __shfl_xor(v, 16);
            v += __shfl_xor(v, 32);
            if (quad == 0) atomicAdd(&S[colbase + st * 16 + l16], v);
        }
    }

    // ---- last-block finalize (ticket pattern); skipped if no counter ----
    if (done == nullptr) return;
    __threadfence();            // release our S atomics
    __syncthreads();
    unsigned int* s_ticket = (unsigned int*)tile;        // LDS reuse
    float* red = (float*)(tile + 8);
    if (tid == 0)
        *s_ticket = atomicAdd(done, 1u);
    __syncthreads();
    if (*s_ticket == (unsigned)(NBLK - 1)) {
        __threadfence();        // acquire: all other blocks' S atomics visible
        float local = 0.0f;
        #pragma unroll
        for (int k = 0; k < N_ROWS / 256; k++) {
            int i = k * 256 + tid;
            float rp = rawp[i];
            float Sv = __hip_atomic_load(&S[i], __ATOMIC_RELAXED, __HIP_MEMORY_SCOPE_AGENT);
            float pclip = fminf(fmaxf(rp, -1.0f), 1.0f);
            float psim = 2.0f * pclip;
            Sv += (rp >= PHI) ? __expf(psim - 2.0f) : 0.0f;
            local += 2.0f + logf(Sv) - psim;
        }
        #pragma unroll
        for (int off = 32; off; off >>= 1) local += __shfl_xor(local, off);
        if (lane == 0) red[wave] = local;
        __syncthreads();
        if (tid == 0)
            out[0] = (red[0] + red[1] + red[2] + red[3]) * (1.0f / (float)N_ROWS);
    }
}

// Fallback finalize (only launched when workspace has no room for the ticket
// counter): loss = mean(2 + log(S_i + pos-correction) - P_i)
__global__ __launch_bounds__(256) void finalize_kernel(
        const float* __restrict__ S, const float* __restrict__ rawp,
        float* __restrict__ out) {
    __shared__ float red[4];
    int i = blockIdx.x * 256 + threadIdx.x;
    float rp = rawp[i];
    float pclip = fminf(fmaxf(rp, -1.0f), 1.0f);
    float psim = 2.0f * pclip;
    float Sv = S[i] + ((rp >= PHI) ? __expf(psim - 2.0f) : 0.0f);
    float v = 2.0f + logf(Sv) - psim;
    #pragma unroll
    for (int off = 32; off; off >>= 1) v += __shfl_xor(v, off);
    int lane = threadIdx.x & 63, wave = threadIdx.x >> 6;
    if (lane == 0) red[wave] = v;
    __syncthreads();
    if (threadIdx.x == 0) {
        float t = red[0] + red[1] + red[2] + red[3];
        atomicAdd(out, t * (1.0f / (float)N_ROWS));
    }
}

extern "C" void kernel_launch(void* const* d_in, const int* in_sizes, int n_in,
                              void* d_out, int out_size, void* d_ws, size_t ws_size,
                              hipStream_t stream) {
    const float* feat = (const float*)d_in[0];
    float* out = (float*)d_out;

    unsigned short* X = (unsigned short*)d_ws;
    float* S = (float*)((char*)d_ws + (size_t)N_ROWS * D_DIM * 2);
    float* rawp = S + N_ROWS;

    // Ticket counter only if workspace actually has room for it (defensive:
    // a 4-byte overflow past the prior session's footprint would page-fault).
    size_t need = (size_t)N_ROWS * D_DIM * 2   // X
                + (size_t)N_ROWS * 4           // S
                + (size_t)N_ROWS * 4           // rawp
                + 16;                          // done (+ padding)
    unsigned int* done = (ws_size >= need) ? (unsigned int*)(rawp + N_ROWS)
                                           : nullptr;

    norm_pos_kernel<<<B_ROWS / 4, 256, 0, stream>>>(feat, X, S, rawp, out, done);
    sym_sim_kernel<<<NBLK, 256, 0, stream>>>(X, S, rawp, out, done);
    if (done == nullptr)
        finalize_kernel<<<N_ROWS / 256, 256, 0, stream>>>(S, rawp, out);
}

// Round 3
// 147.745 us; speedup vs baseline: 1.6228x; 1.6228x over previous
//
#include <hip/hip_runtime.h>
#include <hip/hip_bf16.h>

// Problem constants
#define B_ROWS 4096
#define N_ROWS 8192
#define D_DIM 256
#define PHI 0.95f
// exp(sim-2) = exp2((2*raw-2)*log2e) = exp2(raw*C1 - C1)
#define C1 2.8853900817779268f

// Symmetric tiling: upper-triangle blocks of 128x128 rows x cols.
#define TILE 128
#define T_TILES (N_ROWS / TILE)                 // 64
#define NBLK (T_TILES * (T_TILES + 1) / 2)      // 2080

typedef __attribute__((ext_vector_type(8))) short short8;    // 8 x bf16
typedef __attribute__((ext_vector_type(4))) float floatx4;   // MFMA C/D

static __device__ __forceinline__ unsigned short f2bf(float f) {
    unsigned u = __builtin_bit_cast(unsigned, f);
    unsigned r = (u + 0x7fffu + ((u >> 16) & 1u)) >> 16;   // RNE
    return (unsigned short)r;
}
static __device__ __forceinline__ float bf2f(unsigned short s) {
    unsigned u = ((unsigned)s) << 16;
    return __builtin_bit_cast(float, u);
}
static __device__ __forceinline__ float fast_exp2(float x) {
#if __has_builtin(__builtin_amdgcn_exp2f)
    return __builtin_amdgcn_exp2f(x);
#else
    return __expf(x * 0.6931471805599453f);
#endif
}

// Kernel 1: fused normalize + positive-pair dot (verified round 2, absmax 0).
// Positive partner of row i (view 0) is row i+B (view 1) == the SAME feature
// row's other view, adjacent 256 floats in memory. One wave per pair.
__global__ __launch_bounds__(256) void norm_pos_kernel(
        const float* __restrict__ feat, unsigned short* __restrict__ X,
        float* __restrict__ S, float* __restrict__ rawp,
        float* __restrict__ out) {
    int pair = blockIdx.x * 4 + (threadIdx.x >> 6);   // 0..4095
    int lane = threadIdx.x & 63;
    const float* src = feat + (size_t)pair * (2 * D_DIM);
    float4 v0 = ((const float4*)src)[lane];           // view 0
    float4 v1 = ((const float4*)(src + D_DIM))[lane]; // view 1
    float ss0 = v0.x * v0.x + v0.y * v0.y + v0.z * v0.z + v0.w * v0.w;
    float ss1 = v1.x * v1.x + v1.y * v1.y + v1.z * v1.z + v1.w * v1.w;
    #pragma unroll
    for (int off = 32; off; off >>= 1) {
        ss0 += __shfl_xor(ss0, off);
        ss1 += __shfl_xor(ss1, off);
    }
    float inv0 = 1.0f / fmaxf(sqrtf(ss0), 1e-12f);
    float inv1 = 1.0f / fmaxf(sqrtf(ss1), 1e-12f);
    ushort4 o0, o1;
    o0.x = f2bf(v0.x * inv0); o0.y = f2bf(v0.y * inv0);
    o0.z = f2bf(v0.z * inv0); o0.w = f2bf(v0.w * inv0);
    o1.x = f2bf(v1.x * inv1); o1.y = f2bf(v1.y * inv1);
    o1.z = f2bf(v1.z * inv1); o1.w = f2bf(v1.w * inv1);
    ((ushort4*)(X + (size_t)pair * D_DIM))[lane] = o0;
    ((ushort4*)(X + (size_t)(pair + B_ROWS) * D_DIM))[lane] = o1;
    // pos dot, same numerics as baseline pos_kernel (bf16 values, fp32 accum)
    float d = bf2f(o0.x) * bf2f(o1.x) + bf2f(o0.y) * bf2f(o1.y)
            + bf2f(o0.z) * bf2f(o1.z) + bf2f(o0.w) * bf2f(o1.w);
    #pragma unroll
    for (int off = 32; off; off >>= 1) d += __shfl_xor(d, off);
    if (lane == 0) {
        rawp[pair] = d; rawp[pair + B_ROWS] = d;   // symmetric
        S[pair] = 0.0f; S[pair + B_ROWS] = 0.0f;
    }
    if (blockIdx.x == 0 && threadIdx.x == 0) out[0] = 0.0f;
}

// Kernel 2: symmetric Gram + masked exp-sum, NO LDS / NO barrier / NO fence.
// One block per upper-triangle tile pair (I,J), J>=I, 128x128. 4 waves in a
// 2x2 quadrant layout, each wave 64 rows x 64 cols. Because the Gram is
// X*X^T, the MFMA B-fragment layout (lane=col n, quad spans k) is IDENTICAL
// to the A-fragment layout, so both operands load directly from global X
// (L2-resident, 4 MB). K-outer register tiling: per K-step, 4 A-frags +
// 4 B-frags feed 16 MFMAs (2:1 MFMA:load), 1-deep manual prefetch.
__global__ __launch_bounds__(256, 2) void sym_sim_kernel(
        const unsigned short* __restrict__ X, float* __restrict__ S) {
    const int tid  = threadIdx.x;
    const int wave = tid >> 6;
    const int lane = tid & 63;
    const int quad = lane >> 4;
    const int l16  = lane & 15;

    // upper-triangle decode (verified round 2):
    // off(I) = I*(2T-I+1)/2, J = I + (bid - off(I))
    const int bid = (int)blockIdx.x;
    int I = (int)((2.0f * T_TILES + 1.0f
             - sqrtf((float)((2 * T_TILES + 1) * (2 * T_TILES + 1) - 8 * bid))) * 0.5f);
    while (((I + 1) * (2 * T_TILES - I)) / 2 <= bid) I++;
    while ((I * (2 * T_TILES - I + 1)) / 2 > bid) I--;
    const int J = I + bid - (I * (2 * T_TILES - I + 1)) / 2;

    const int wr = wave >> 1;   // row half 0..1
    const int wc = wave & 1;    // col half 0..1
    const int rowbase = I * TILE + wr * 64;
    const int colbase = J * TILE + wc * 64;

    // Fragment base pointers: lane holds frag[idx=l16][k=quad*8..quad*8+7]
    const unsigned short* abase = X + (size_t)(rowbase + l16) * D_DIM + quad * 8;
    const unsigned short* bbase = X + (size_t)(colbase + l16) * D_DIM + quad * 8;

    floatx4 acc[4][4];          // [row-set s][col-set st]
    #pragma unroll
    for (int s = 0; s < 4; s++)
        #pragma unroll
        for (int st = 0; st < 4; st++) acc[s][st] = (floatx4){0.f, 0.f, 0.f, 0.f};

    short8 a_cur[4], b_cur[4];
    #pragma unroll
    for (int s = 0; s < 4; s++)
        a_cur[s] = *(const short8*)(abase + (size_t)s * 16 * D_DIM);
    #pragma unroll
    for (int st = 0; st < 4; st++)
        b_cur[st] = *(const short8*)(bbase + (size_t)st * 16 * D_DIM);

    #pragma unroll
    for (int ks = 0; ks < 8; ks++) {            // K = 256, 32 per step
        short8 a_nxt[4], b_nxt[4];
        if (ks < 7) {
            #pragma unroll
            for (int s = 0; s < 4; s++)
                a_nxt[s] = *(const short8*)(abase + (size_t)s * 16 * D_DIM + (ks + 1) * 32);
            #pragma unroll
            for (int st = 0; st < 4; st++)
                b_nxt[st] = *(const short8*)(bbase + (size_t)st * 16 * D_DIM + (ks + 1) * 32);
        }
        #pragma unroll
        for (int s = 0; s < 4; s++)
            #pragma unroll
            for (int st = 0; st < 4; st++)
                acc[s][st] = __builtin_amdgcn_mfma_f32_16x16x32_bf16(a_cur[s], b_cur[st], acc[s][st], 0, 0, 0);
        if (ks < 7) {
            #pragma unroll
            for (int s = 0; s < 4; s++) a_cur[s] = a_nxt[s];
            #pragma unroll
            for (int st = 0; st < 4; st++) b_cur[st] = b_nxt[st];
        }
    }

    // Epilogue: masked exp feeds row-acc AND col-acc (element (s,st,r) is
    // row rowbase+s*16+quad*4+r, col colbase+st*16+l16).
    float sacc[4][4];
    #pragma unroll
    for (int s = 0; s < 4; s++)
        #pragma unroll
        for (int r = 0; r < 4; r++) sacc[s][r] = 0.0f;
    float cacc[4];
    #pragma unroll
    for (int st = 0; st < 4; st++) {
        float cs = 0.0f;
        #pragma unroll
        for (int s = 0; s < 4; s++)
            #pragma unroll
            for (int r = 0; r < 4; r++) {
                float raw = acc[s][st][r];
                float e = fast_exp2(fmaf(raw, C1, -C1));
                e = (raw < PHI) ? e : 0.0f;
                sacc[s][r] += e;
                cs += e;
            }
        cacc[st] = cs;
    }

    // Row sums: reduce over the 16 cols (l16) of each quad-group (verified).
    #pragma unroll
    for (int s = 0; s < 4; s++)
        #pragma unroll
        for (int r = 0; r < 4; r++) {
            float v = sacc[s][r];
            v += __shfl_xor(v, 1);
            v += __shfl_xor(v, 2);
            v += __shfl_xor(v, 4);
            v += __shfl_xor(v, 8);
            if (l16 == r) atomicAdd(&S[rowbase + s * 16 + quad * 4 + r], v);
        }
    // Transpose (col) sums: reduce over quads; skip on diagonal tiles
    // (a diagonal tile already counts every (i,j) of its square once).
    if (I != J) {
        #pragma unroll
        for (int st = 0; st < 4; st++) {
            float v = cacc[st];
            v += __shfl_xor(v, 16);
            v += __shfl_xor(v, 32);
            if (quad == 0) atomicAdd(&S[colbase + st * 16 + l16], v);
        }
    }
}

// Kernel 3: loss = mean(2 + log(S_i + pos-correction) - P_i)  (baseline)
__global__ __launch_bounds__(256) void finalize_kernel(
        const float* __restrict__ S, const float* __restrict__ rawp,
        float* __restrict__ out) {
    __shared__ float red[4];
    int i = blockIdx.x * 256 + threadIdx.x;
    float rp = rawp[i];
    float pclip = fminf(fmaxf(rp, -1.0f), 1.0f);
    float psim = 2.0f * pclip;
    float Sv = S[i] + ((rp >= PHI) ? __expf(psim - 2.0f) : 0.0f);
    float v = 2.0f + logf(Sv) - psim;
    #pragma unroll
    for (int off = 32; off; off >>= 1) v += __shfl_xor(v, off);
    int lane = threadIdx.x & 63, wave = threadIdx.x >> 6;
    if (lane == 0) red[wave] = v;
    __syncthreads();
    if (threadIdx.x == 0) {
        float t = red[0] + red[1] + red[2] + red[3];
        atomicAdd(out, t * (1.0f / (float)N_ROWS));
    }
}

extern "C" void kernel_launch(void* const* d_in, const int* in_sizes, int n_in,
                              void* d_out, int out_size, void* d_ws, size_t ws_size,
                              hipStream_t stream) {
    const float* feat = (const float*)d_in[0];
    float* out = (float*)d_out;

    unsigned short* X = (unsigned short*)d_ws;
    float* S = (float*)((char*)d_ws + (size_t)N_ROWS * D_DIM * 2);
    float* rawp = S + N_ROWS;

    norm_pos_kernel<<<B_ROWS / 4, 256, 0, stream>>>(feat, X, S, rawp, out);
    sym_sim_kernel<<<NBLK, 256, 0, stream>>>(X, S);
    finalize_kernel<<<N_ROWS / 256, 256, 0, stream>>>(S, rawp, out);
}